// Round 2
// baseline (555.464 us; speedup 1.0000x reference)
//
#include <hip/hip_runtime.h>
#include <hip/hip_bf16.h>

typedef __attribute__((ext_vector_type(8))) __bf16 bfrag;
typedef __attribute__((ext_vector_type(4))) float ffrag;
typedef __attribute__((ext_vector_type(8))) unsigned short us8;
typedef __attribute__((ext_vector_type(4))) unsigned short us4;

#define DEVINL static __device__ __forceinline__
#define MFMA(a, b, c) __builtin_amdgcn_mfma_f32_16x16x32_bf16((a), (b), (c), 0, 0, 0)

DEVINL unsigned short f2bf(float f) {
    union { float f; unsigned u; } v; v.f = f;
    unsigned r = v.u + 0x7fffu + ((v.u >> 16) & 1u);
    return (unsigned short)(r >> 16);
}
DEVINL float bf2f(unsigned short h) {
    union { unsigned u; float f; } v; v.u = ((unsigned)h) << 16;
    return v.f;
}

// ---------------------------------------------------------------------------
// Kernel 1: pack weights to bf16 hi[512][256] (rows 0-127 Wq, 128-255 Wk,
// 256-511 Wv) + lo residual for the Q,K rows only. Gather biases.
// ---------------------------------------------------------------------------
__global__ void kprep(const float* __restrict__ Wq, const float* __restrict__ Wk,
                      const float* __restrict__ Wv, const float* __restrict__ bq,
                      const float* __restrict__ bk, const float* __restrict__ bv,
                      unsigned short* __restrict__ Whi, unsigned short* __restrict__ Wlo,
                      float* __restrict__ ball) {
    int t = blockIdx.x * 256 + threadIdx.x;      // 512*256 threads
    int o = t >> 8, c = t & 255;
    float v = (o < 128) ? Wq[o * 256 + c]
            : (o < 256) ? Wk[(o - 128) * 256 + c]
                        : Wv[(o - 256) * 256 + c];
    unsigned short hi = f2bf(v);
    Whi[t] = hi;
    if (o < 256) Wlo[t] = f2bf(v - bf2f(hi));
    if (c == 0) {
        ball[o] = (o < 128) ? bq[o] : (o < 256) ? bk[o - 128] : bv[o - 256];
    }
}

// ---------------------------------------------------------------------------
// Kernel 2: 1x1 conv projections via MFMA, split-precision for Q,K.
// Q,K written [b][n][128] as hi+lo bf16; V written [b][co][n] bf16 (hi only).
// ---------------------------------------------------------------------------
__global__ __launch_bounds__(256) void kproj(const float* __restrict__ x,
                                             const unsigned short* __restrict__ Whi,
                                             const unsigned short* __restrict__ Wlo,
                                             const float* __restrict__ ball,
                                             unsigned short* __restrict__ Qh,
                                             unsigned short* __restrict__ Ql,
                                             unsigned short* __restrict__ Kh,
                                             unsigned short* __restrict__ Kl,
                                             unsigned short* __restrict__ Vb) {
    __shared__ unsigned short sXh[64 * 256];      // [pixel][ch], XOR-swizzled
    __shared__ unsigned short sXl[64 * 256];
    const int t = threadIdx.x;
    const int lane = t & 63;
    const int wv = t >> 6;
    const int l16 = lane & 15;
    const int lg = lane >> 4;
    const int b = blockIdx.x >> 6;
    const int n0 = (blockIdx.x & 63) << 6;
    const float* xb = x + (size_t)b * 256 * 4096 + n0;

    // stage x^T tile (hi+lo): thread = pixel p (=lane), channel group by wave
    const int p = lane;
#pragma unroll
    for (int ci = 0; ci < 8; ++ci) {
        const int c0 = ci * 32 + (wv << 3);
        __align__(16) unsigned short th[8], tl[8];
#pragma unroll
        for (int j = 0; j < 8; ++j) {
            float v = xb[(size_t)(c0 + j) * 4096 + p];
            th[j] = f2bf(v);
            tl[j] = f2bf(v - bf2f(th[j]));
        }
        const int off = p * 256 + (c0 ^ ((p & 7) << 3));
        *(us8*)&sXh[off] = *(const us8*)th;
        *(us8*)&sXl[off] = *(const us8*)tl;
    }
    __syncthreads();

    ffrag accQK[16];  // D[pixel 16*wv+..][o=16ct+l16], o in 0..255 (Q,K)
    ffrag accV[16];   // D[o=256+64*wv+16mt+..][pixel 16*c2+l16]
#pragma unroll
    for (int i = 0; i < 16; ++i) {
        accQK[i] = ffrag{0.f, 0.f, 0.f, 0.f};
        accV[i]  = ffrag{0.f, 0.f, 0.f, 0.f};
    }
    const int rowx = 16 * wv + l16;
#pragma unroll
    for (int step = 0; step < 8; ++step) {
        const int cb = step * 32 + (lg << 3);
        const int offx = rowx * 256 + (cb ^ ((rowx & 7) << 3));
        bfrag axh = *(const bfrag*)&sXh[offx];
        bfrag axl = *(const bfrag*)&sXl[offx];
#pragma unroll
        for (int ct = 0; ct < 16; ++ct) {
            const int o = ct * 16 + l16;
            bfrag bwh = *(const bfrag*)&Whi[o * 256 + cb];
            bfrag bwl = *(const bfrag*)&Wlo[o * 256 + cb];
            accQK[ct] = MFMA(axh, bwh, accQK[ct]);
            accQK[ct] = MFMA(axh, bwl, accQK[ct]);
            accQK[ct] = MFMA(axl, bwh, accQK[ct]);
        }
        bfrag bx[4];
#pragma unroll
        for (int c2 = 0; c2 < 4; ++c2) {
            const int px = c2 * 16 + l16;
            bx[c2] = *(const bfrag*)&sXh[px * 256 + (cb ^ ((px & 7) << 3))];
        }
#pragma unroll
        for (int mt = 0; mt < 4; ++mt) {
            const int o = 256 + 64 * wv + 16 * mt + l16;
            bfrag aw = *(const bfrag*)&Whi[o * 256 + cb];
#pragma unroll
            for (int c2 = 0; c2 < 4; ++c2)
                accV[mt * 4 + c2] = MFMA(aw, bx[c2], accV[mt * 4 + c2]);
        }
    }

    // epilogue: +bias, split to hi+lo bf16, store
#pragma unroll
    for (int ct = 0; ct < 16; ++ct) {
        const int o = ct * 16 + l16;
        const float bias = ball[o];
        unsigned short* dhi = (o < 128) ? Qh : Kh;
        unsigned short* dlo = (o < 128) ? Ql : Kl;
        const int oo = o & 127;
#pragma unroll
        for (int r = 0; r < 4; ++r) {
            const int px = 16 * wv + (lg << 2) + r;
            const float val = accQK[ct][r] + bias;
            unsigned short hi = f2bf(val);
            const size_t idx = ((size_t)b * 4096 + n0 + px) * 128 + oo;
            dhi[idx] = hi;
            dlo[idx] = f2bf(val - bf2f(hi));
        }
    }
#pragma unroll
    for (int mt = 0; mt < 4; ++mt) {
#pragma unroll
        for (int r = 0; r < 4; ++r) {
            const int o = 64 * wv + 16 * mt + (lg << 2) + r;
            const float bias = ball[256 + o];
#pragma unroll
            for (int c2 = 0; c2 < 4; ++c2) {
                const int px = c2 * 16 + l16;
                Vb[((size_t)b * 256 + o) * 4096 + n0 + px] = f2bf(accV[mt * 4 + c2][r] + bias);
            }
        }
    }
}

// ---------------------------------------------------------------------------
// Kernel 3: fused flash attention, split-precision QK^T.
// 256 blocks = 4 batches x 64 query tiles, XCD-swizzled (batch per XCD pair).
// 4 waves x 16 query rows each; 64-key tiles; online softmax.
// ---------------------------------------------------------------------------
__global__ __launch_bounds__(256) void kattn(const unsigned short* __restrict__ Qh,
                                             const unsigned short* __restrict__ Ql,
                                             const unsigned short* __restrict__ Kh,
                                             const unsigned short* __restrict__ Kl,
                                             const unsigned short* __restrict__ Vb,
                                             unsigned short* __restrict__ wOut) {
    __shared__ unsigned short sQh[64 * 128];  // [q][ch]   swizzled
    __shared__ unsigned short sQl[64 * 128];
    __shared__ unsigned short sKh[64 * 128];  // [k][ch]   swizzled
    __shared__ unsigned short sKl[64 * 128];
    __shared__ unsigned short sV[256 * 64];   // [co][k]   swizzled
    __shared__ unsigned short sP[64 * 64];    // [q][k]    swizzled (wave-private rows)
    const int t = threadIdx.x;
    const int lane = t & 63;
    const int wv = t >> 6;
    const int l16 = lane & 15;
    const int lg = lane >> 4;
    const int blk = blockIdx.x;
    const int b = (blk & 7) >> 1;                      // XCD pair -> batch
    const int qt = ((blk >> 3) << 1) | (blk & 1);
    const int n0 = qt << 6;
    const unsigned short* Qhg = Qh + ((size_t)b * 4096 + n0) * 128;
    const unsigned short* Qlg = Ql + ((size_t)b * 4096 + n0) * 128;
    const unsigned short* Khg = Kh + (size_t)b * 4096 * 128;
    const unsigned short* Klg = Kl + (size_t)b * 4096 * 128;
    const unsigned short* Vg  = Vb + (size_t)b * 256 * 4096;

    // stage Q once (hi+lo)
    {
        const int rb = t >> 4;
        const int c0 = (t & 15) << 3;
#pragma unroll
        for (int i = 0; i < 4; ++i) {
            int row = i * 16 + rb;
            int off = row * 128 + (c0 ^ ((row & 7) << 3));
            *(us8*)&sQh[off] = *(const us8*)&Qhg[row * 128 + c0];
            *(us8*)&sQl[off] = *(const us8*)&Qlg[row * 128 + c0];
        }
    }

    float m_[4], l_[4];
    ffrag O[16];
#pragma unroll
    for (int r = 0; r < 4; ++r) { m_[r] = -3e38f; l_[r] = 0.f; }
#pragma unroll
    for (int i = 0; i < 16; ++i) O[i] = ffrag{0.f, 0.f, 0.f, 0.f};

    const int rowq = 16 * wv + l16;   // A-frag row for S and P
    __syncthreads();
    bfrag aqh[4], aql[4];
#pragma unroll
    for (int st = 0; st < 4; ++st) {
        const int off = rowq * 128 + ((st * 32 + (lg << 3)) ^ ((rowq & 7) << 3));
        aqh[st] = *(const bfrag*)&sQh[off];
        aql[st] = *(const bfrag*)&sQl[off];
    }

    for (int kt0 = 0; kt0 < 64; ++kt0) {
        const int k0 = kt0 << 6;
        // ---- stage K tile hi+lo (32 KB) + V tile (32 KB)
        {
            const int rb = t >> 4;
            const int c0 = (t & 15) << 3;
#pragma unroll
            for (int i = 0; i < 4; ++i) {
                int row = i * 16 + rb;
                int off = row * 128 + (c0 ^ ((row & 7) << 3));
                *(us8*)&sKh[off] = *(const us8*)&Khg[(size_t)(k0 + row) * 128 + c0];
                *(us8*)&sKl[off] = *(const us8*)&Klg[(size_t)(k0 + row) * 128 + c0];
            }
            const int cob = t >> 3;
            const int ke0 = (t & 7) << 3;
#pragma unroll
            for (int i = 0; i < 8; ++i) {
                int co = i * 32 + cob;
                *(us8*)&sV[co * 64 + (ke0 ^ ((co & 7) << 3))] =
                    *(const us8*)&Vg[(size_t)co * 4096 + k0 + ke0];
            }
        }
        __syncthreads();

        // ---- S = Q K^T  (48 MFMA / wave: hi*hi + hi*lo + lo*hi)
        ffrag S[4];
#pragma unroll
        for (int i = 0; i < 4; ++i) S[i] = ffrag{0.f, 0.f, 0.f, 0.f};
#pragma unroll
        for (int kt = 0; kt < 4; ++kt) {
            const int rowk = kt * 16 + l16;
#pragma unroll
            for (int st = 0; st < 4; ++st) {
                const int off = rowk * 128 + ((st * 32 + (lg << 3)) ^ ((rowk & 7) << 3));
                bfrag bkh = *(const bfrag*)&sKh[off];
                bfrag bkl = *(const bfrag*)&sKl[off];
                S[kt] = MFMA(aqh[st], bkh, S[kt]);
                S[kt] = MFMA(aqh[st], bkl, S[kt]);
                S[kt] = MFMA(aql[st], bkh, S[kt]);
            }
        }

        // ---- online softmax (rows = 4*lg+r, keys across l16 and kt)
        float pexp[16];
#pragma unroll
        for (int r = 0; r < 4; ++r) {
            float mx = fmaxf(fmaxf(S[0][r], S[1][r]), fmaxf(S[2][r], S[3][r]));
            mx = fmaxf(mx, __shfl_xor(mx, 1));
            mx = fmaxf(mx, __shfl_xor(mx, 2));
            mx = fmaxf(mx, __shfl_xor(mx, 4));
            mx = fmaxf(mx, __shfl_xor(mx, 8));
            const float newm = fmaxf(m_[r], mx);
            const float sc = __expf(m_[r] - newm);
            m_[r] = newm;
            float rs = 0.f;
#pragma unroll
            for (int kt = 0; kt < 4; ++kt) {
                float e = __expf(S[kt][r] - newm);
                pexp[kt * 4 + r] = e;
                rs += e;
            }
            rs += __shfl_xor(rs, 1);
            rs += __shfl_xor(rs, 2);
            rs += __shfl_xor(rs, 4);
            rs += __shfl_xor(rs, 8);
            l_[r] = l_[r] * sc + rs;
#pragma unroll
            for (int ct = 0; ct < 16; ++ct) O[ct][r] *= sc;
        }

        // ---- P -> LDS (wave-private rows; same-wave ds ordering is safe)
#pragma unroll
        for (int kt = 0; kt < 4; ++kt) {
#pragma unroll
            for (int r = 0; r < 4; ++r) {
                const int prow = 16 * wv + (lg << 2) + r;
                const int pcol = kt * 16 + l16;
                sP[prow * 64 + (pcol ^ ((prow & 7) << 3))] = f2bf(pexp[kt * 4 + r]);
            }
        }

        // ---- O += P V  (32 MFMA / wave)
#pragma unroll
        for (int st = 0; st < 2; ++st) {
            bfrag pa = *(const bfrag*)&sP[rowq * 64 + ((st * 32 + (lg << 3)) ^ ((rowq & 7) << 3))];
#pragma unroll
            for (int ct = 0; ct < 16; ++ct) {
                const int co = ct * 16 + l16;
                bfrag bv_ = *(const bfrag*)&sV[co * 64 + ((st * 32 + (lg << 3)) ^ ((co & 7) << 3))];
                O[ct] = MFMA(pa, bv_, O[ct]);
            }
        }
        __syncthreads();   // protect sK/sV from next-iter staging
    }

    // ---- epilogue: O/l -> bf16 -> w[b][n][co]
#pragma unroll
    for (int r = 0; r < 4; ++r) {
        const float inv = 1.f / l_[r];
        const int px = 16 * wv + (lg << 2) + r;
#pragma unroll
        for (int ct = 0; ct < 16; ++ct) {
            const int co = ct * 16 + l16;
            wOut[((size_t)b * 4096 + n0 + px) * 256 + co] = f2bf(O[ct][r] * inv);
        }
    }
}

// ---------------------------------------------------------------------------
// Kernel 4: BN partial stats (deterministic): block = 16384 contiguous elems,
// thread t owns channel t; partials written per block.
// ---------------------------------------------------------------------------
__global__ void kstats(const unsigned short* __restrict__ w, float* __restrict__ partial) {
    const int t = threadIdx.x;
    const size_t base = (size_t)blockIdx.x * 16384;
    float s = 0.f, s2 = 0.f;
    for (int i = 0; i < 64; ++i) {
        float v = bf2f(w[base + i * 256 + t]);
        s += v;
        s2 += v * v;
    }
    partial[(size_t)blockIdx.x * 512 + t] = s;
    partial[(size_t)blockIdx.x * 512 + 256 + t] = s2;
}

// Kernel 4b: reduce partials in fixed order -> stats[512]
__global__ void kstats2(const float* __restrict__ partial, float* __restrict__ stats) {
    const int t = threadIdx.x;   // 0..511
    float s = 0.f;
    for (int blk = 0; blk < 256; ++blk) s += partial[(size_t)blk * 512 + t];
    stats[t] = s;
}

// ---------------------------------------------------------------------------
// Kernel 5: apply BN + transpose [b][n][co] -> out[b][co][n] fp32.
// ---------------------------------------------------------------------------
__global__ __launch_bounds__(256) void kapply(const unsigned short* __restrict__ w,
                                              const float* __restrict__ stats,
                                              const float* __restrict__ gamma,
                                              const float* __restrict__ beta,
                                              float* __restrict__ out) {
    __shared__ unsigned short sw[64 * 260];     // 64 rows, pad 256->260
    __shared__ float sscale[256];
    __shared__ float sshift[256];
    const int t = threadIdx.x;
    const int b = blockIdx.x >> 6;
    const int n0 = (blockIdx.x & 63) << 6;
    const unsigned short* wb = w + ((size_t)b * 4096 + n0) * 256;
#pragma unroll
    for (int i = 0; i < 16; ++i) {
        const int chunk = i * 256 + t;
        const int p = chunk >> 6;
        const int cq = chunk & 63;
        *(us4*)&sw[p * 260 + cq * 4] = *(const us4*)&wb[p * 256 + cq * 4];
    }
    {
        const float mean = stats[t] * (1.f / 16384.f);
        const float var = stats[256 + t] * (1.f / 16384.f) - mean * mean;
        const float inv = rsqrtf(var + 1e-5f);
        const float sc = gamma[t] * inv;
        sscale[t] = sc;
        sshift[t] = beta[t] - mean * sc;
    }
    __syncthreads();
    const int p = t & 63;
    const int cg = t >> 6;
    float* ob = out + (size_t)b * 256 * 4096 + n0;
#pragma unroll 4
    for (int i = 0; i < 64; ++i) {
        const int co = i * 4 + cg;
        const float v = bf2f(sw[p * 260 + co]);
        ob[(size_t)co * 4096 + p] = v * sscale[co] + sshift[co];
    }
}

// ---------------------------------------------------------------------------
extern "C" void kernel_launch(void* const* d_in, const int* in_sizes, int n_in,
                              void* d_out, int out_size, void* d_ws, size_t ws_size,
                              hipStream_t stream) {
    const float* x     = (const float*)d_in[0];
    const float* Wq    = (const float*)d_in[1];
    const float* bq    = (const float*)d_in[2];
    const float* Wk    = (const float*)d_in[3];
    const float* bk    = (const float*)d_in[4];
    const float* Wv    = (const float*)d_in[5];
    const float* bv    = (const float*)d_in[6];
    const float* gamma = (const float*)d_in[7];
    const float* beta  = (const float*)d_in[8];
    float* out = (float*)d_out;

    char* ws = (char*)d_ws;
    // layout (bytes):
    unsigned short* Whi   = (unsigned short*)(ws + 0x0);        // 256 KB
    unsigned short* Wlo   = (unsigned short*)(ws + 0x40000);    // 128 KB
    float*          ball  = (float*)(ws + 0x60000);             // 2 KB
    float*          stats = (float*)(ws + 0x60800);             // 2 KB
    float*          part  = (float*)(ws + 0x61000);             // 512 KB
    unsigned short* Qh    = (unsigned short*)(ws + 0x100000);   // 4 MB
    unsigned short* Ql    = (unsigned short*)(ws + 0x500000);   // 4 MB
    unsigned short* Kh    = (unsigned short*)(ws + 0x900000);   // 4 MB
    unsigned short* Kl    = (unsigned short*)(ws + 0xD00000);   // 4 MB
    unsigned short* Vb    = (unsigned short*)(ws + 0x1100000);  // 8 MB
    unsigned short* wbuf  = (unsigned short*)(ws + 0x1900000);  // 8 MB
    if (ws_size < 0x2100000) return;  // need 33 MB scratch

    kprep<<<512, 256, 0, stream>>>(Wq, Wk, Wv, bq, bk, bv, Whi, Wlo, ball);
    kproj<<<256, 256, 0, stream>>>(x, Whi, Wlo, ball, Qh, Ql, Kh, Kl, Vb);
    kattn<<<256, 256, 0, stream>>>(Qh, Ql, Kh, Kl, Vb, wbuf);
    kstats<<<256, 256, 0, stream>>>(wbuf, part);
    kstats2<<<1, 512, 0, stream>>>(part, stats);
    kapply<<<256, 256, 0, stream>>>(wbuf, stats, gamma, beta, out);
}

// Round 3
// 230.609 us; speedup vs baseline: 2.4087x; 2.4087x over previous
//
#include <hip/hip_runtime.h>
#include <hip/hip_bf16.h>

typedef __attribute__((ext_vector_type(8))) __bf16 bfrag;
typedef __attribute__((ext_vector_type(4))) float ffrag;
typedef __attribute__((ext_vector_type(8))) unsigned short us8;
typedef __attribute__((ext_vector_type(4))) unsigned short us4;

#define DEVINL static __device__ __forceinline__
#define MFMA(a, b, c) __builtin_amdgcn_mfma_f32_16x16x32_bf16((a), (b), (c), 0, 0, 0)

DEVINL unsigned short f2bf(float f) {
    union { float f; unsigned u; } v; v.f = f;
    unsigned r = v.u + 0x7fffu + ((v.u >> 16) & 1u);
    return (unsigned short)(r >> 16);
}
DEVINL float bf2f(unsigned short h) {
    union { unsigned u; float f; } v; v.u = ((unsigned)h) << 16;
    return v.f;
}

// DPP rotate-reduce within 16-lane rows (VALU-speed, no LDS pipe).
template <int C>
DEVINL float dppmov(float x) {
    union { float f; int i; } a, b;
    a.f = x;
    b.i = __builtin_amdgcn_update_dpp(0, a.i, C, 0xf, 0xf, true);
    return b.f;
}
DEVINL float rowmax16(float v) {
    v = fmaxf(v, dppmov<0x121>(v));   // row_ror:1
    v = fmaxf(v, dppmov<0x122>(v));   // row_ror:2
    v = fmaxf(v, dppmov<0x124>(v));   // row_ror:4
    v = fmaxf(v, dppmov<0x128>(v));   // row_ror:8
    return v;
}
DEVINL float rowsum16(float v) {
    v += dppmov<0x121>(v);
    v += dppmov<0x122>(v);
    v += dppmov<0x124>(v);
    v += dppmov<0x128>(v);
    return v;
}

// async global->LDS, 16B per lane; LDS dest = wave-uniform base + lane*16
DEVINL void gload_lds16(const unsigned short* g, unsigned short* l) {
    __builtin_amdgcn_global_load_lds(
        (const __attribute__((address_space(1))) unsigned int*)g,
        (__attribute__((address_space(3))) unsigned int*)l, 16, 0, 0);
}

// ---------------------------------------------------------------------------
// Kernel 1: pack weights to bf16 hi[512][256] (rows 0-127 Wq, 128-255 Wk,
// 256-511 Wv) + lo residual for the Q,K rows only. Gather biases.
// ---------------------------------------------------------------------------
__global__ void kprep(const float* __restrict__ Wq, const float* __restrict__ Wk,
                      const float* __restrict__ Wv, const float* __restrict__ bq,
                      const float* __restrict__ bk, const float* __restrict__ bv,
                      unsigned short* __restrict__ Whi, unsigned short* __restrict__ Wlo,
                      float* __restrict__ ball) {
    int t = blockIdx.x * 256 + threadIdx.x;      // 512*256 threads
    int o = t >> 8, c = t & 255;
    float v = (o < 128) ? Wq[o * 256 + c]
            : (o < 256) ? Wk[(o - 128) * 256 + c]
                        : Wv[(o - 256) * 256 + c];
    unsigned short hi = f2bf(v);
    Whi[t] = hi;
    if (o < 256) Wlo[t] = f2bf(v - bf2f(hi));
    if (c == 0) {
        ball[o] = (o < 128) ? bq[o] : (o < 256) ? bk[o - 128] : bv[o - 256];
    }
}

// ---------------------------------------------------------------------------
// Kernel 2: 1x1 conv projections via MFMA, split-precision for Q,K.
// Q,K written [b][n][128] as hi+lo bf16; V written [b][co][n] bf16 (hi only).
// ---------------------------------------------------------------------------
__global__ __launch_bounds__(256) void kproj(const float* __restrict__ x,
                                             const unsigned short* __restrict__ Whi,
                                             const unsigned short* __restrict__ Wlo,
                                             const float* __restrict__ ball,
                                             unsigned short* __restrict__ Qh,
                                             unsigned short* __restrict__ Ql,
                                             unsigned short* __restrict__ Kh,
                                             unsigned short* __restrict__ Kl,
                                             unsigned short* __restrict__ Vb) {
    __shared__ unsigned short sXh[64 * 256];      // [pixel][ch], XOR-swizzled
    __shared__ unsigned short sXl[64 * 256];
    const int t = threadIdx.x;
    const int lane = t & 63;
    const int wv = t >> 6;
    const int l16 = lane & 15;
    const int lg = lane >> 4;
    const int b = blockIdx.x >> 6;
    const int n0 = (blockIdx.x & 63) << 6;
    const float* xb = x + (size_t)b * 256 * 4096 + n0;

    // stage x^T tile (hi+lo): thread = pixel p (=lane), channel group by wave
    const int p = lane;
#pragma unroll
    for (int ci = 0; ci < 8; ++ci) {
        const int c0 = ci * 32 + (wv << 3);
        __align__(16) unsigned short th[8], tl[8];
#pragma unroll
        for (int j = 0; j < 8; ++j) {
            float v = xb[(size_t)(c0 + j) * 4096 + p];
            th[j] = f2bf(v);
            tl[j] = f2bf(v - bf2f(th[j]));
        }
        const int off = p * 256 + (c0 ^ ((p & 7) << 3));
        *(us8*)&sXh[off] = *(const us8*)th;
        *(us8*)&sXl[off] = *(const us8*)tl;
    }
    __syncthreads();

    ffrag accQK[16];  // D[pixel 16*wv+..][o=16ct+l16], o in 0..255 (Q,K)
    ffrag accV[16];   // D[o=256+64*wv+16mt+..][pixel 16*c2+l16]
#pragma unroll
    for (int i = 0; i < 16; ++i) {
        accQK[i] = ffrag{0.f, 0.f, 0.f, 0.f};
        accV[i]  = ffrag{0.f, 0.f, 0.f, 0.f};
    }
    const int rowx = 16 * wv + l16;
#pragma unroll
    for (int step = 0; step < 8; ++step) {
        const int cb = step * 32 + (lg << 3);
        const int offx = rowx * 256 + (cb ^ ((rowx & 7) << 3));
        bfrag axh = *(const bfrag*)&sXh[offx];
        bfrag axl = *(const bfrag*)&sXl[offx];
#pragma unroll
        for (int ct = 0; ct < 16; ++ct) {
            const int o = ct * 16 + l16;
            bfrag bwh = *(const bfrag*)&Whi[o * 256 + cb];
            bfrag bwl = *(const bfrag*)&Wlo[o * 256 + cb];
            accQK[ct] = MFMA(axh, bwh, accQK[ct]);
            accQK[ct] = MFMA(axh, bwl, accQK[ct]);
            accQK[ct] = MFMA(axl, bwh, accQK[ct]);
        }
        bfrag bx[4];
#pragma unroll
        for (int c2 = 0; c2 < 4; ++c2) {
            const int px = c2 * 16 + l16;
            bx[c2] = *(const bfrag*)&sXh[px * 256 + (cb ^ ((px & 7) << 3))];
        }
#pragma unroll
        for (int mt = 0; mt < 4; ++mt) {
            const int o = 256 + 64 * wv + 16 * mt + l16;
            bfrag aw = *(const bfrag*)&Whi[o * 256 + cb];
#pragma unroll
            for (int c2 = 0; c2 < 4; ++c2)
                accV[mt * 4 + c2] = MFMA(aw, bx[c2], accV[mt * 4 + c2]);
        }
    }

    // epilogue: +bias, split to hi+lo bf16, store
#pragma unroll
    for (int ct = 0; ct < 16; ++ct) {
        const int o = ct * 16 + l16;
        const float bias = ball[o];
        unsigned short* dhi = (o < 128) ? Qh : Kh;
        unsigned short* dlo = (o < 128) ? Ql : Kl;
        const int oo = o & 127;
#pragma unroll
        for (int r = 0; r < 4; ++r) {
            const int px = 16 * wv + (lg << 2) + r;
            const float val = accQK[ct][r] + bias;
            unsigned short hi = f2bf(val);
            const size_t idx = ((size_t)b * 4096 + n0 + px) * 128 + oo;
            dhi[idx] = hi;
            dlo[idx] = f2bf(val - bf2f(hi));
        }
    }
#pragma unroll
    for (int mt = 0; mt < 4; ++mt) {
#pragma unroll
        for (int r = 0; r < 4; ++r) {
            const int o = 64 * wv + 16 * mt + (lg << 2) + r;
            const float bias = ball[256 + o];
#pragma unroll
            for (int c2 = 0; c2 < 4; ++c2) {
                const int px = c2 * 16 + l16;
                Vb[((size_t)b * 256 + o) * 4096 + n0 + px] = f2bf(accV[mt * 4 + c2][r] + bias);
            }
        }
    }
}

// ---------------------------------------------------------------------------
// Kernel 3: fused flash attention, split-precision QK^T.
// 512 blocks = 4 batches x 128 query tiles of 32 rows (XCD-swizzled: batch
// per XCD pair). 4 waves = 2 q-groups x 2 key-halves; 64-key LDS tiles staged
// via global_load_lds (linear dest + inverse-swizzled source); DPP softmax;
// defer-rescale; key-half merge in LDS at the end. 68KB LDS -> 2 blocks/CU.
// ---------------------------------------------------------------------------
__global__ __launch_bounds__(256, 2) void kattn(const unsigned short* __restrict__ Qh,
                                                const unsigned short* __restrict__ Ql,
                                                const unsigned short* __restrict__ Kh,
                                                const unsigned short* __restrict__ Kl,
                                                const unsigned short* __restrict__ Vb,
                                                unsigned short* __restrict__ wOut) {
    __shared__ __align__(16) unsigned short smem[34816];  // 68KB
    unsigned short* sKh = smem;              // [64][128]  16KB
    unsigned short* sKl = smem + 8192;       // [64][128]  16KB
    unsigned short* sV  = smem + 16384;      // [256][64]  32KB
    unsigned short* sP  = smem + 32768;      // [32][64]    4KB

    const int t = threadIdx.x;
    const int lane = t & 63;
    const int wv = t >> 6;
    const int qg = wv & 1;        // 16-row query group
    const int kh = wv >> 1;       // 32-key half
    const int l16 = lane & 15;
    const int lg = lane >> 4;

    const int blk = blockIdx.x;
    const int x8 = blk & 7;
    const int b = x8 >> 1;                          // batch per XCD pair
    const int qt = ((blk >> 3) << 1) | (x8 & 1);    // 0..127
    const int n0 = qt << 5;

    const unsigned short* Khg = Kh + (size_t)b * 4096 * 128;
    const unsigned short* Klg = Kl + (size_t)b * 4096 * 128;
    const unsigned short* Vg  = Vb + (size_t)b * 256 * 4096;

    // ---- Q fragments direct from global (once)
    bfrag aqh[4], aql[4];
    {
        const size_t gq = ((size_t)b * 4096 + n0 + 16 * qg + l16) * 128;
#pragma unroll
        for (int st = 0; st < 4; ++st) {
            const size_t off = gq + st * 32 + lg * 8;
            aqh[st] = *(const bfrag*)&Qh[off];
            aql[st] = *(const bfrag*)&Ql[off];
        }
    }

    float m_[4], l_[4];
    ffrag O[16];
#pragma unroll
    for (int r = 0; r < 4; ++r) { m_[r] = -3e38f; l_[r] = 0.f; }
#pragma unroll
    for (int i = 0; i < 16; ++i) O[i] = ffrag{0.f, 0.f, 0.f, 0.f};

    const int rowq = 16 * qg + l16;             // A-frag row (local q)
    const int pcol = kh * 32 + lg * 8;          // k-chunk base for P/V frags

    // staging lane constants
    const int klr = lane >> 4;                  // K: row-in-4
    const int kcb = (lane & 15) ^ klr;          // K: chunk base (^4 on odd j)
    const int vlr = lane >> 3;                  // V: row-in-8
    const int vch = (lane & 7) ^ vlr;           // V: chunk

    for (int it = 0; it < 64; ++it) {
        const int k0 = it << 6;
        __syncthreads();     // all waves done reading previous tile
        // ---- stage K hi/lo + V via async global->LDS (16 issues per wave)
        if (kh == 0) {
            const unsigned short* src = (qg == 0) ? Khg : Klg;
            unsigned short* dst = (qg == 0) ? sKh : sKl;
#pragma unroll
            for (int j = 0; j < 16; ++j) {
                const int trow = 4 * j + klr;
                const int chunk = kcb ^ ((j & 1) << 2);
                gload_lds16(src + (size_t)(k0 + trow) * 128 + chunk * 8,
                            dst + 4 * j * 128);
            }
        } else {
            const int cobase = qg * 128;
#pragma unroll
            for (int j = 0; j < 16; ++j) {
                const int co = cobase + 8 * j + vlr;
                gload_lds16(Vg + (size_t)co * 4096 + k0 + vch * 8,
                            sV + (cobase + 8 * j) * 64);
            }
        }
        __syncthreads();     // drains vmcnt -> tile ready

        // ---- S = Q K^T over this wave's 32 keys (24 MFMA)
        ffrag S[2];
        S[0] = ffrag{0.f, 0.f, 0.f, 0.f};
        S[1] = ffrag{0.f, 0.f, 0.f, 0.f};
#pragma unroll
        for (int kt = 0; kt < 2; ++kt) {
            const int rowk = kh * 32 + kt * 16 + l16;
            const int swz = (rowk & 7) << 3;
#pragma unroll
            for (int st = 0; st < 4; ++st) {
                const int off = rowk * 128 + ((st * 32 + lg * 8) ^ swz);
                bfrag bkh = *(const bfrag*)&sKh[off];
                bfrag bkl = *(const bfrag*)&sKl[off];
                S[kt] = MFMA(aqh[st], bkh, S[kt]);
                S[kt] = MFMA(aqh[st], bkl, S[kt]);
                S[kt] = MFMA(aql[st], bkh, S[kt]);
            }
        }

        // ---- online softmax (DPP reduce over l16; rows = 4*lg+r)
        float mx[4];
        bool grow = false;
#pragma unroll
        for (int r = 0; r < 4; ++r) {
            mx[r] = rowmax16(fmaxf(S[0][r], S[1][r]));
            grow = grow || (mx[r] > m_[r]);
        }
        if (__any(grow)) {   // rescale (rare after warmup)
#pragma unroll
            for (int r = 0; r < 4; ++r) {
                const float newm = fmaxf(m_[r], mx[r]);
                const float sc = __expf(m_[r] - newm);
                m_[r] = newm;
                l_[r] *= sc;
#pragma unroll
                for (int ct = 0; ct < 16; ++ct) O[ct][r] *= sc;
            }
        }
        float e0[4], e1[4];
#pragma unroll
        for (int r = 0; r < 4; ++r) {
            e0[r] = __expf(S[0][r] - m_[r]);
            e1[r] = __expf(S[1][r] - m_[r]);
            l_[r] += rowsum16(e0[r] + e1[r]);
        }

        // ---- P -> LDS (wave-private rows+cols; same-wave ordering)
#pragma unroll
        for (int r = 0; r < 4; ++r) {
            const int prow = 16 * qg + 4 * lg + r;
            const int pswz = (prow & 7) << 3;
            sP[prow * 64 + ((kh * 32 + l16) ^ pswz)] = f2bf(e0[r]);
            sP[prow * 64 + ((kh * 32 + 16 + l16) ^ pswz)] = f2bf(e1[r]);
        }

        // ---- O += P V over this wave's 32 keys (16 MFMA)
        bfrag pa = *(const bfrag*)&sP[rowq * 64 + (pcol ^ ((rowq & 7) << 3))];
#pragma unroll
        for (int ct = 0; ct < 16; ++ct) {
            const int co = ct * 16 + l16;
            bfrag bv_ = *(const bfrag*)&sV[co * 64 + (pcol ^ ((co & 7) << 3))];
            O[ct] = MFMA(pa, bv_, O[ct]);
        }
    }

    // ---- merge key-halves via LDS, write out
    __syncthreads();
    float* sO  = (float*)smem;                 // [32][256] f32 = 32KB
    float* sml = (float*)(smem + 16384);       // [32][2]
    if (kh == 1) {
#pragma unroll
        for (int r = 0; r < 4; ++r) {
            const int row = 16 * qg + 4 * lg + r;
            if (l16 == 0) { sml[row * 2] = m_[r]; sml[row * 2 + 1] = l_[r]; }
        }
#pragma unroll
        for (int ct = 0; ct < 16; ++ct)
#pragma unroll
            for (int r = 0; r < 4; ++r)
                sO[(16 * qg + 4 * lg + r) * 256 + ct * 16 + l16] = O[ct][r];
    }
    __syncthreads();
    if (kh == 0) {
        float fa[4], fc[4];
#pragma unroll
        for (int r = 0; r < 4; ++r) {
            const int row = 16 * qg + 4 * lg + r;
            const float pm = sml[row * 2], pl = sml[row * 2 + 1];
            const float M = fmaxf(m_[r], pm);
            const float a = __expf(m_[r] - M), c = __expf(pm - M);
            const float inv = 1.f / (a * l_[r] + c * pl);
            fa[r] = a * inv; fc[r] = c * inv;
        }
#pragma unroll
        for (int ct = 0; ct < 16; ++ct) {
#pragma unroll
            for (int r = 0; r < 4; ++r) {
                const int px = 16 * qg + 4 * lg + r;
                const int co = ct * 16 + l16;
                const float val = fa[r] * O[ct][r] + fc[r] * sO[px * 256 + co];
                wOut[((size_t)b * 4096 + n0 + px) * 256 + co] = f2bf(val);
            }
        }
    }
}

// ---------------------------------------------------------------------------
// Kernel 4: BN partial stats (deterministic): block = 16384 contiguous elems,
// thread t owns channel t; partials written per block.
// ---------------------------------------------------------------------------
__global__ void kstats(const unsigned short* __restrict__ w, float* __restrict__ partial) {
    const int t = threadIdx.x;
    const size_t base = (size_t)blockIdx.x * 16384;
    float s = 0.f, s2 = 0.f;
    for (int i = 0; i < 64; ++i) {
        float v = bf2f(w[base + i * 256 + t]);
        s += v;
        s2 += v * v;
    }
    partial[(size_t)blockIdx.x * 512 + t] = s;
    partial[(size_t)blockIdx.x * 512 + 256 + t] = s2;
}

// Kernel 4b: reduce partials in fixed order -> stats[512]
__global__ void kstats2(const float* __restrict__ partial, float* __restrict__ stats) {
    const int t = threadIdx.x;   // 0..511
    float s = 0.f;
    for (int blk = 0; blk < 256; ++blk) s += partial[(size_t)blk * 512 + t];
    stats[t] = s;
}

// ---------------------------------------------------------------------------
// Kernel 5: apply BN + transpose [b][n][co] -> out[b][co][n] fp32.
// ---------------------------------------------------------------------------
__global__ __launch_bounds__(256) void kapply(const unsigned short* __restrict__ w,
                                              const float* __restrict__ stats,
                                              const float* __restrict__ gamma,
                                              const float* __restrict__ beta,
                                              float* __restrict__ out) {
    __shared__ unsigned short sw[64 * 260];     // 64 rows, pad 256->260
    __shared__ float sscale[256];
    __shared__ float sshift[256];
    const int t = threadIdx.x;
    const int b = blockIdx.x >> 6;
    const int n0 = (blockIdx.x & 63) << 6;
    const unsigned short* wb = w + ((size_t)b * 4096 + n0) * 256;
#pragma unroll
    for (int i = 0; i < 16; ++i) {
        const int chunk = i * 256 + t;
        const int p = chunk >> 6;
        const int cq = chunk & 63;
        *(us4*)&sw[p * 260 + cq * 4] = *(const us4*)&wb[p * 256 + cq * 4];
    }
    {
        const float mean = stats[t] * (1.f / 16384.f);
        const float var = stats[256 + t] * (1.f / 16384.f) - mean * mean;
        const float inv = rsqrtf(var + 1e-5f);
        const float sc = gamma[t] * inv;
        sscale[t] = sc;
        sshift[t] = beta[t] - mean * sc;
    }
    __syncthreads();
    const int p = t & 63;
    const int cg = t >> 6;
    float* ob = out + (size_t)b * 256 * 4096 + n0;
#pragma unroll 4
    for (int i = 0; i < 64; ++i) {
        const int co = i * 4 + cg;
        const float v = bf2f(sw[p * 260 + co]);
        ob[(size_t)co * 4096 + p] = v * sscale[co] + sshift[co];
    }
}

// ---------------------------------------------------------------------------
extern "C" void kernel_launch(void* const* d_in, const int* in_sizes, int n_in,
                              void* d_out, int out_size, void* d_ws, size_t ws_size,
                              hipStream_t stream) {
    const float* x     = (const float*)d_in[0];
    const float* Wq    = (const float*)d_in[1];
    const float* bq    = (const float*)d_in[2];
    const float* Wk    = (const float*)d_in[3];
    const float* bk    = (const float*)d_in[4];
    const float* Wv    = (const float*)d_in[5];
    const float* bv    = (const float*)d_in[6];
    const float* gamma = (const float*)d_in[7];
    const float* beta  = (const float*)d_in[8];
    float* out = (float*)d_out;

    char* ws = (char*)d_ws;
    unsigned short* Whi   = (unsigned short*)(ws + 0x0);        // 256 KB
    unsigned short* Wlo   = (unsigned short*)(ws + 0x40000);    // 128 KB
    float*          ball  = (float*)(ws + 0x60000);             // 2 KB
    float*          stats = (float*)(ws + 0x60800);             // 2 KB
    float*          part  = (float*)(ws + 0x61000);             // 512 KB
    unsigned short* Qh    = (unsigned short*)(ws + 0x100000);   // 4 MB
    unsigned short* Ql    = (unsigned short*)(ws + 0x500000);   // 4 MB
    unsigned short* Kh    = (unsigned short*)(ws + 0x900000);   // 4 MB
    unsigned short* Kl    = (unsigned short*)(ws + 0xD00000);   // 4 MB
    unsigned short* Vb    = (unsigned short*)(ws + 0x1100000);  // 8 MB
    unsigned short* wbuf  = (unsigned short*)(ws + 0x1900000);  // 8 MB
    if (ws_size < 0x2100000) return;  // need 33 MB scratch

    kprep<<<512, 256, 0, stream>>>(Wq, Wk, Wv, bq, bk, bv, Whi, Wlo, ball);
    kproj<<<256, 256, 0, stream>>>(x, Whi, Wlo, ball, Qh, Ql, Kh, Kl, Vb);
    kattn<<<512, 256, 0, stream>>>(Qh, Ql, Kh, Kl, Vb, wbuf);
    kstats<<<256, 256, 0, stream>>>(wbuf, part);
    kstats2<<<1, 512, 0, stream>>>(part, stats);
    kapply<<<256, 256, 0, stream>>>(wbuf, stats, gamma, beta, out);
}

// Round 4
// 196.409 us; speedup vs baseline: 2.8281x; 1.1741x over previous
//
#include <hip/hip_runtime.h>
#include <hip/hip_bf16.h>

typedef __attribute__((ext_vector_type(8))) _Float16 hfrag;
typedef __attribute__((ext_vector_type(4))) float ffrag;
typedef __attribute__((ext_vector_type(8))) unsigned short us8;
typedef __attribute__((ext_vector_type(4))) unsigned short us4;

#define DEVINL static __device__ __forceinline__
#define MFMAH(a, b, c) __builtin_amdgcn_mfma_f32_16x16x32_f16((a), (b), (c), 0, 0, 0)

// DPP rotate-reduce within 16-lane rows (VALU-speed, no LDS pipe).
template <int C>
DEVINL float dppmov(float x) {
    union { float f; int i; } a, b;
    a.f = x;
    b.i = __builtin_amdgcn_update_dpp(0, a.i, C, 0xf, 0xf, true);
    return b.f;
}
DEVINL float rowmax16(float v) {
    v = fmaxf(v, dppmov<0x121>(v));   // row_ror:1
    v = fmaxf(v, dppmov<0x122>(v));   // row_ror:2
    v = fmaxf(v, dppmov<0x124>(v));   // row_ror:4
    v = fmaxf(v, dppmov<0x128>(v));   // row_ror:8
    return v;
}
DEVINL float rowsum16(float v) {
    v += dppmov<0x121>(v);
    v += dppmov<0x122>(v);
    v += dppmov<0x124>(v);
    v += dppmov<0x128>(v);
    return v;
}

// async global->LDS, 16B per lane; LDS dest = wave-uniform base + lane*16
DEVINL void gload_lds16(const _Float16* g, _Float16* l) {
    __builtin_amdgcn_global_load_lds(
        (const __attribute__((address_space(1))) unsigned int*)g,
        (__attribute__((address_space(3))) unsigned int*)l, 16, 0, 0);
}

// ---------------------------------------------------------------------------
// Kernel 1: pack weights to fp16 [512][256] (rows 0-127 Wq, 128-255 Wk,
// 256-511 Wv), gather biases.
// ---------------------------------------------------------------------------
__global__ void kprep(const float* __restrict__ Wq, const float* __restrict__ Wk,
                      const float* __restrict__ Wv, const float* __restrict__ bq,
                      const float* __restrict__ bk, const float* __restrict__ bv,
                      _Float16* __restrict__ Wh, float* __restrict__ ball) {
    int t = blockIdx.x * 256 + threadIdx.x;      // 512*256 threads
    int o = t >> 8, c = t & 255;
    float v = (o < 128) ? Wq[o * 256 + c]
            : (o < 256) ? Wk[(o - 128) * 256 + c]
                        : Wv[(o - 256) * 256 + c];
    Wh[t] = (_Float16)v;
    if (c == 0) {
        ball[o] = (o < 128) ? bq[o] : (o < 256) ? bk[o - 128] : bv[o - 256];
    }
}

// ---------------------------------------------------------------------------
// Kernel 2: 1x1 conv projections via fp16 MFMA.
// Q,K written [b][n][128] fp16; V written [b][co][n] fp16 (operand swap).
// ---------------------------------------------------------------------------
__global__ __launch_bounds__(256) void kproj(const float* __restrict__ x,
                                             const _Float16* __restrict__ Wh,
                                             const float* __restrict__ ball,
                                             _Float16* __restrict__ Qb,
                                             _Float16* __restrict__ Kb,
                                             _Float16* __restrict__ Vb) {
    __shared__ _Float16 sX[64 * 256];             // [pixel][ch], XOR-swizzled, 32KB
    const int t = threadIdx.x;
    const int lane = t & 63;
    const int wv = t >> 6;
    const int l16 = lane & 15;
    const int lg = lane >> 4;
    const int b = blockIdx.x >> 6;
    const int n0 = (blockIdx.x & 63) << 6;
    const float* xb = x + (size_t)b * 256 * 4096 + n0;

    // stage x^T tile: thread = pixel p (=lane), channel group by wave
    const int p = lane;
#pragma unroll
    for (int ci = 0; ci < 8; ++ci) {
        const int c0 = ci * 32 + (wv << 3);
        __align__(16) _Float16 th[8];
#pragma unroll
        for (int j = 0; j < 8; ++j) th[j] = (_Float16)xb[(size_t)(c0 + j) * 4096 + p];
        *(us8*)&sX[p * 256 + (c0 ^ ((p & 7) << 3))] = *(const us8*)th;
    }
    __syncthreads();

    ffrag accQK[16];  // D[pixel 16*wv+..][o=16ct+l16], o in 0..255 (Q,K)
    ffrag accV[16];   // D[o=256+64*wv+16mt+..][pixel 16*c2+l16]
#pragma unroll
    for (int i = 0; i < 16; ++i) {
        accQK[i] = ffrag{0.f, 0.f, 0.f, 0.f};
        accV[i]  = ffrag{0.f, 0.f, 0.f, 0.f};
    }
    const int rowx = 16 * wv + l16;
#pragma unroll
    for (int step = 0; step < 8; ++step) {
        const int cb = step * 32 + (lg << 3);
        hfrag ax = *(const hfrag*)&sX[rowx * 256 + (cb ^ ((rowx & 7) << 3))];
#pragma unroll
        for (int ct = 0; ct < 16; ++ct) {
            const int o = ct * 16 + l16;
            hfrag bw = *(const hfrag*)&Wh[o * 256 + cb];
            accQK[ct] = MFMAH(ax, bw, accQK[ct]);
        }
        hfrag bx[4];
#pragma unroll
        for (int c2 = 0; c2 < 4; ++c2) {
            const int px = c2 * 16 + l16;
            bx[c2] = *(const hfrag*)&sX[px * 256 + (cb ^ ((px & 7) << 3))];
        }
#pragma unroll
        for (int mt = 0; mt < 4; ++mt) {
            const int o = 256 + 64 * wv + 16 * mt + l16;
            hfrag aw = *(const hfrag*)&Wh[o * 256 + cb];
#pragma unroll
            for (int c2 = 0; c2 < 4; ++c2)
                accV[mt * 4 + c2] = MFMAH(aw, bx[c2], accV[mt * 4 + c2]);
        }
    }

    // epilogue: +bias, fp16, store
#pragma unroll
    for (int ct = 0; ct < 16; ++ct) {
        const int o = ct * 16 + l16;
        const float bias = ball[o];
        _Float16* dst = (o < 128) ? Qb : Kb;
        const int oo = o & 127;
#pragma unroll
        for (int r = 0; r < 4; ++r) {
            const int px = 16 * wv + (lg << 2) + r;
            dst[((size_t)b * 4096 + n0 + px) * 128 + oo] = (_Float16)(accQK[ct][r] + bias);
        }
    }
#pragma unroll
    for (int mt = 0; mt < 4; ++mt) {
#pragma unroll
        for (int r = 0; r < 4; ++r) {
            const int o = 64 * wv + 16 * mt + (lg << 2) + r;
            const float bias = ball[256 + o];
#pragma unroll
            for (int c2 = 0; c2 < 4; ++c2) {
                const int px = c2 * 16 + l16;
                Vb[((size_t)b * 256 + o) * 4096 + n0 + px] = (_Float16)(accV[mt * 4 + c2][r] + bias);
            }
        }
    }
}

// ---------------------------------------------------------------------------
// Kernel 3: fused flash attention, fp16, counted-vmcnt 3-barrier pipeline.
// 512 blocks = 4 batches x 128 query tiles of 32 rows (XCD-swizzled: batch
// per XCD pair). 4 waves = 2 q-groups x 2 key-halves; per iter: issue K(4)
// then V(8) chunks per wave; vmcnt(8)+bar -> QK+softmax overlaps V loads;
// vmcnt(0)+bar -> PV.  52KB LDS -> 2 blocks/CU.
// ---------------------------------------------------------------------------
__global__ __launch_bounds__(256, 2) void kattn(const _Float16* __restrict__ Qb,
                                                const _Float16* __restrict__ Kb,
                                                const _Float16* __restrict__ Vb,
                                                _Float16* __restrict__ wOut) {
    __shared__ __align__(16) _Float16 smem[26624];  // 52KB
    _Float16* sK = smem;              // [64][128]  16KB
    _Float16* sV = smem + 8192;       // [256][64]  32KB
    _Float16* sP = smem + 24576;      // [32][64]    4KB

    const int t = threadIdx.x;
    const int lane = t & 63;
    const int wv = t >> 6;
    const int qg = wv & 1;        // 16-row query group
    const int kh = wv >> 1;       // 32-key half
    const int l16 = lane & 15;
    const int lg = lane >> 4;

    const int blk = blockIdx.x;
    const int x8 = blk & 7;
    const int b = x8 >> 1;                          // batch per XCD pair
    const int qt = ((blk >> 3) << 1) | (x8 & 1);    // 0..127
    const int n0 = qt << 5;

    const _Float16* Kg = Kb + (size_t)b * 4096 * 128;
    const _Float16* Vg = Vb + (size_t)b * 256 * 4096;

    // ---- Q fragments direct from global (once)
    hfrag aq[4];
    {
        const size_t gq = ((size_t)b * 4096 + n0 + 16 * qg + l16) * 128;
#pragma unroll
        for (int st = 0; st < 4; ++st)
            aq[st] = *(const hfrag*)&Qb[gq + st * 32 + lg * 8];
    }

    float m_[4], l_[4];
    ffrag O[16];
#pragma unroll
    for (int r = 0; r < 4; ++r) { m_[r] = -3e38f; l_[r] = 0.f; }
#pragma unroll
    for (int i = 0; i < 16; ++i) O[i] = ffrag{0.f, 0.f, 0.f, 0.f};

    const int rowq = 16 * qg + l16;             // A-frag row (local q)
    const int pcol = kh * 32 + lg * 8;          // k-chunk base for P/V frags

    // staging lane constants
    const int krow_in = lane >> 4;              // K: row-in-chunk (0..3)
    const int kcol = lane & 15;                 // K: col chunk index
    const int vrow_in = lane >> 3;              // V: row-in-chunk (0..7)
    const int vcol = lane & 7;                  // V: col chunk index

    for (int it = 0; it < 64; ++it) {
        const int k0 = it << 6;
        __builtin_amdgcn_s_barrier();           // everyone done reading prev tiles
        __builtin_amdgcn_sched_barrier(0);
        // ---- issue K chunks (4), then V chunks (8): 12 gload_lds per wave
#pragma unroll
        for (int j = 0; j < 4; ++j) {
            const int c = 4 * wv + j;           // 0..15
            const int row = 4 * c + krow_in;
            gload_lds16(Kg + (size_t)(k0 + row) * 128 + ((kcol ^ (row & 7)) << 3),
                        sK + c * 512);
        }
        __builtin_amdgcn_sched_barrier(0);      // pin K-before-V issue order
#pragma unroll
        for (int j = 0; j < 8; ++j) {
            const int cv = 8 * wv + j;          // 0..31
            const int co = 8 * cv + vrow_in;
            gload_lds16(Vg + (size_t)co * 4096 + k0 + ((vcol ^ (co & 7)) << 3),
                        sV + cv * 512);
        }
        asm volatile("s_waitcnt vmcnt(8)" ::: "memory");   // K landed (V in flight)
        __builtin_amdgcn_s_barrier();
        __builtin_amdgcn_sched_barrier(0);

        // ---- S = Q K^T over this wave's 32 keys (8 MFMA), V loads underneath
        ffrag S[2];
        S[0] = ffrag{0.f, 0.f, 0.f, 0.f};
        S[1] = ffrag{0.f, 0.f, 0.f, 0.f};
#pragma unroll
        for (int kt = 0; kt < 2; ++kt) {
            const int rowk = kh * 32 + kt * 16 + l16;
            const int swz = (rowk & 7) << 3;
#pragma unroll
            for (int st = 0; st < 4; ++st) {
                hfrag bk = *(const hfrag*)&sK[rowk * 128 + ((st * 32 + lg * 8) ^ swz)];
                S[kt] = MFMAH(aq[st], bk, S[kt]);
            }
        }

        // ---- online softmax (DPP reduce over l16; rows = 4*lg+r)
        float mx[4];
        bool grow = false;
#pragma unroll
        for (int r = 0; r < 4; ++r) {
            mx[r] = rowmax16(fmaxf(S[0][r], S[1][r]));
            grow = grow || (mx[r] > m_[r]);
        }
        if (__any(grow)) {
#pragma unroll
            for (int r = 0; r < 4; ++r) {
                const float newm = fmaxf(m_[r], mx[r]);
                const float sc = __expf(m_[r] - newm);
                m_[r] = newm;
                l_[r] *= sc;
#pragma unroll
                for (int ct = 0; ct < 16; ++ct) O[ct][r] *= sc;
            }
        }
        float e0[4], e1[4];
#pragma unroll
        for (int r = 0; r < 4; ++r) {
            e0[r] = __expf(S[0][r] - m_[r]);
            e1[r] = __expf(S[1][r] - m_[r]);
            l_[r] += rowsum16(e0[r] + e1[r]);
        }

        // ---- P -> LDS fp16 (wave-private rows+cols; same-wave ordering)
#pragma unroll
        for (int r = 0; r < 4; ++r) {
            const int prow = 16 * qg + 4 * lg + r;
            const int pswz = (prow & 7) << 3;
            sP[prow * 64 + ((kh * 32 + l16) ^ pswz)] = (_Float16)e0[r];
            sP[prow * 64 + ((kh * 32 + 16 + l16) ^ pswz)] = (_Float16)e1[r];
        }

        asm volatile("s_waitcnt vmcnt(0)" ::: "memory");   // V landed
        __builtin_amdgcn_s_barrier();
        __builtin_amdgcn_sched_barrier(0);

        // ---- O += P V over this wave's 32 keys (16 MFMA)
        hfrag pa = *(const hfrag*)&sP[rowq * 64 + (pcol ^ ((rowq & 7) << 3))];
#pragma unroll
        for (int ct = 0; ct < 16; ++ct) {
            const int co = ct * 16 + l16;
            hfrag bv_ = *(const hfrag*)&sV[co * 64 + (pcol ^ ((co & 7) << 3))];
            O[ct] = MFMAH(pa, bv_, O[ct]);
        }
    }

    // ---- merge key-halves via LDS, write out
    __syncthreads();
    float* sO  = (float*)smem;                 // [32][256] f32 = 32KB
    float* sml = (float*)(smem + 16384);       // [32][2]
    if (kh == 1) {
#pragma unroll
        for (int r = 0; r < 4; ++r) {
            const int row = 16 * qg + 4 * lg + r;
            if (l16 == 0) { sml[row * 2] = m_[r]; sml[row * 2 + 1] = l_[r]; }
        }
#pragma unroll
        for (int ct = 0; ct < 16; ++ct)
#pragma unroll
            for (int r = 0; r < 4; ++r)
                sO[(16 * qg + 4 * lg + r) * 256 + ct * 16 + l16] = O[ct][r];
    }
    __syncthreads();
    if (kh == 0) {
        float fa[4], fc[4];
#pragma unroll
        for (int r = 0; r < 4; ++r) {
            const int row = 16 * qg + 4 * lg + r;
            const float pm = sml[row * 2], pl = sml[row * 2 + 1];
            const float M = fmaxf(m_[r], pm);
            const float a = __expf(m_[r] - M), c = __expf(pm - M);
            const float inv = 1.f / (a * l_[r] + c * pl);
            fa[r] = a * inv; fc[r] = c * inv;
        }
#pragma unroll
        for (int ct = 0; ct < 16; ++ct) {
#pragma unroll
            for (int r = 0; r < 4; ++r) {
                const int px = 16 * qg + 4 * lg + r;
                const int co = ct * 16 + l16;
                const float val = fa[r] * O[ct][r] + fc[r] * sO[px * 256 + co];
                wOut[((size_t)b * 4096 + n0 + px) * 256 + co] = (_Float16)val;
            }
        }
    }
}

// ---------------------------------------------------------------------------
// Kernel 4: BN partial stats (deterministic): block = 16384 contiguous elems,
// thread t owns channel t; partials written per block.
// ---------------------------------------------------------------------------
__global__ void kstats(const _Float16* __restrict__ w, float* __restrict__ partial) {
    const int t = threadIdx.x;
    const size_t base = (size_t)blockIdx.x * 16384;
    float s = 0.f, s2 = 0.f;
    for (int i = 0; i < 64; ++i) {
        float v = (float)w[base + i * 256 + t];
        s += v;
        s2 += v * v;
    }
    partial[(size_t)blockIdx.x * 512 + t] = s;
    partial[(size_t)blockIdx.x * 512 + 256 + t] = s2;
}

// Kernel 4b: reduce partials in fixed order -> stats[512], 4 channels/thread
__global__ void kstats2(const float* __restrict__ partial, float* __restrict__ stats) {
    const int t = threadIdx.x;   // 0..127
    ffrag s = ffrag{0.f, 0.f, 0.f, 0.f};
    for (int blk = 0; blk < 256; ++blk) {
        ffrag p = *(const ffrag*)&partial[(size_t)blk * 512 + t * 4];
        s += p;
    }
    *(ffrag*)&stats[t * 4] = s;
}

// ---------------------------------------------------------------------------
// Kernel 5: apply BN + transpose [b][n][co] -> out[b][co][n] fp32.
// ---------------------------------------------------------------------------
__global__ __launch_bounds__(256) void kapply(const _Float16* __restrict__ w,
                                              const float* __restrict__ stats,
                                              const float* __restrict__ gamma,
                                              const float* __restrict__ beta,
                                              float* __restrict__ out) {
    __shared__ _Float16 sw[64 * 260];           // 64 rows, pad 256->260
    __shared__ float sscale[256];
    __shared__ float sshift[256];
    const int t = threadIdx.x;
    const int b = blockIdx.x >> 6;
    const int n0 = (blockIdx.x & 63) << 6;
    const _Float16* wb = w + ((size_t)b * 4096 + n0) * 256;
#pragma unroll
    for (int i = 0; i < 16; ++i) {
        const int chunk = i * 256 + t;
        const int p = chunk >> 6;
        const int cq = chunk & 63;
        *(us4*)&sw[p * 260 + cq * 4] = *(const us4*)&wb[p * 256 + cq * 4];
    }
    {
        const float mean = stats[t] * (1.f / 16384.f);
        const float var = stats[256 + t] * (1.f / 16384.f) - mean * mean;
        const float inv = rsqrtf(var + 1e-5f);
        const float sc = gamma[t] * inv;
        sscale[t] = sc;
        sshift[t] = beta[t] - mean * sc;
    }
    __syncthreads();
    const int p = t & 63;
    const int cg = t >> 6;
    float* ob = out + (size_t)b * 256 * 4096 + n0;
#pragma unroll 4
    for (int i = 0; i < 64; ++i) {
        const int co = i * 4 + cg;
        const float v = (float)sw[p * 260 + co];
        ob[(size_t)co * 4096 + p] = v * sscale[co] + sshift[co];
    }
}

// ---------------------------------------------------------------------------
extern "C" void kernel_launch(void* const* d_in, const int* in_sizes, int n_in,
                              void* d_out, int out_size, void* d_ws, size_t ws_size,
                              hipStream_t stream) {
    const float* x     = (const float*)d_in[0];
    const float* Wq    = (const float*)d_in[1];
    const float* bq    = (const float*)d_in[2];
    const float* Wk    = (const float*)d_in[3];
    const float* bk    = (const float*)d_in[4];
    const float* Wv    = (const float*)d_in[5];
    const float* bv    = (const float*)d_in[6];
    const float* gamma = (const float*)d_in[7];
    const float* beta  = (const float*)d_in[8];
    float* out = (float*)d_out;

    char* ws = (char*)d_ws;
    _Float16* Wh    = (_Float16*)(ws + 0x0);        // 256 KB
    float*    ball  = (float*)(ws + 0x40000);       // 2 KB
    float*    stats = (float*)(ws + 0x40800);       // 2 KB
    float*    part  = (float*)(ws + 0x41000);       // 512 KB
    _Float16* Qb    = (_Float16*)(ws + 0x100000);   // 4 MB
    _Float16* Kb    = (_Float16*)(ws + 0x500000);   // 4 MB
    _Float16* Vb    = (_Float16*)(ws + 0x900000);   // 8 MB
    _Float16* wbuf  = (_Float16*)(ws + 0x1100000);  // 8 MB
    if (ws_size < 0x1900000) return;  // need 25 MB scratch

    kprep<<<512, 256, 0, stream>>>(Wq, Wk, Wv, bq, bk, bv, Wh, ball);
    kproj<<<256, 256, 0, stream>>>(x, Wh, ball, Qb, Kb, Vb);
    kattn<<<512, 256, 0, stream>>>(Qb, Kb, Vb, wbuf);
    kstats<<<256, 256, 0, stream>>>(wbuf, part);
    kstats2<<<1, 128, 0, stream>>>(part, stats);
    kapply<<<256, 256, 0, stream>>>(wbuf, stats, gamma, beta, out);
}